// Round 4
// baseline (608.525 us; speedup 1.0000x reference)
//
#include <hip/hip_runtime.h>
#include <hip/hip_bf16.h>
#include <cstdint>

// out[M,N] = A[M,K] (fp32) x W[N,K] (int8 stored as int32 by harness — verified R1/R2) * scale[N]
// M=8192 N=4096 K=4096
#define M_DIM 8192
#define N_DIM 4096
#define K_DIM 4096

typedef unsigned short u16;
typedef unsigned int u32;
typedef __attribute__((ext_vector_type(8))) short short8;            // 8 x bf16 (4 VGPRs)
typedef __attribute__((ext_vector_type(8))) unsigned short ushort8;  // 16B store unit
typedef __attribute__((ext_vector_type(4))) float floatx4;           // MFMA accumulator

#define AS1 __attribute__((address_space(1)))
#define AS3 __attribute__((address_space(3)))

static __device__ __forceinline__ u16 f2bf(float f) {
    // round-to-nearest-even fp32 -> bf16 (inputs are finite normals)
    u32 x = __float_as_uint(f);
    x += 0x7FFFu + ((x >> 16) & 1u);
    return (u16)(x >> 16);
}

// ---------------- fused prepass: A fp32 -> bf16  and  W int32 -> bf16 ----------------
// One launch; 16B stores. int8 values are exact in bf16.
__global__ void cvt_fused_kernel(const float4* __restrict__ A, const int4* __restrict__ W,
                                 ushort8* __restrict__ Abf, ushort8* __restrict__ Wbf,
                                 int nA8, int nW8) {
    int i = blockIdx.x * blockDim.x + threadIdx.x;
    const int stride = gridDim.x * blockDim.x;
    const int total = nA8 + nW8;
    for (; i < total; i += stride) {
        if (i < nA8) {
            float4 f0 = A[2 * i], f1 = A[2 * i + 1];
            ushort8 u;
            u[0] = f2bf(f0.x); u[1] = f2bf(f0.y); u[2] = f2bf(f0.z); u[3] = f2bf(f0.w);
            u[4] = f2bf(f1.x); u[5] = f2bf(f1.y); u[6] = f2bf(f1.z); u[7] = f2bf(f1.w);
            Abf[i] = u;
        } else {
            const int j = i - nA8;
            int4 w0 = W[2 * j], w1 = W[2 * j + 1];
            ushort8 u;
            u[0] = f2bf((float)w0.x); u[1] = f2bf((float)w0.y);
            u[2] = f2bf((float)w0.z); u[3] = f2bf((float)w0.w);
            u[4] = f2bf((float)w1.x); u[5] = f2bf((float)w1.y);
            u[6] = f2bf((float)w1.z); u[7] = f2bf((float)w1.w);
            Wbf[j] = u;
        }
    }
}

// ---------------- main GEMM: m97 structure + XOR swizzle + double-buffered LDS ----------------
// 128x128 tile, BK=32, 256 threads = 4 waves in 2x2, each wave 4x4 of 16x16x32 bf16 MFMA.
// Double buffer: prefetch tile kt+1 (global_load_lds) into buf 1-p before computing tile kt
// from buf p; ONE barrier per kt. The vmcnt(0) drain at the barrier overlaps with the whole
// ds_read+MFMA block instead of stalling cold.
// Swizzle: LDS position p of row r holds global 16B chunk p ^ ((r>>1)&3) -> bank-conflict-free
// (verified R3: SQ_LDS_BANK_CONFLICT 3.35e7 -> 0).
__global__ void __launch_bounds__(256)
gemm_bf16_kernel(const u16* __restrict__ A, const u16* __restrict__ W,
                 const float* __restrict__ scaler, float* __restrict__ out) {
    __shared__ u16 As[2][128 * 32];   // 2 x 8 KB
    __shared__ u16 Bs[2][128 * 32];   // 2 x 8 KB  (32 KB total -> 5 blocks/CU by LDS)

    const int tid  = threadIdx.x;
    const int wave = tid >> 6;
    const int lane = tid & 63;
    const int r = lane & 15;       // MFMA row/col within 16
    const int q = lane >> 4;       // quad 0..3

    const int mBase = blockIdx.y * 128;
    const int nBase = blockIdx.x * 128;
    const int waveM = wave >> 1;   // 0..1
    const int waveN = wave & 1;    // 0..1

    floatx4 acc[4][4] = {};

    // staging: lane covers tile row (tid>>2), 16B chunk position (tid&3); source chunk is
    // XOR-swizzled (same 64B line -> coalescing unchanged; dst stays lane-contiguous).
    const int rowA  = tid >> 2;                  // 0..63
    const int swzW  = (rowA >> 1) & 3;
    const int chunk = (tid & 3) ^ swzW;          // global chunk to fetch
    const u16* aSrc0 = A + (size_t)(mBase + rowA) * K_DIM + chunk * 8;
    const u16* aSrc1 = A + (size_t)(mBase + 64 + rowA) * K_DIM + chunk * 8;
    const u16* bSrc0 = W + (size_t)(nBase + rowA) * K_DIM + chunk * 8;
    const u16* bSrc1 = W + (size_t)(nBase + 64 + rowA) * K_DIM + chunk * 8;
    char* aDst0 = (char*)&As[0][0] + wave * 1024;       // HW adds lane*16
    char* aDst1 = (char*)&As[0][0] + 4096 + wave * 1024;
    char* bDst0 = (char*)&Bs[0][0] + wave * 1024;
    char* bDst1 = (char*)&Bs[0][0] + 4096 + wave * 1024;

    // fragment read bases: lane reads [row = panel + r][chunk q^swz], swz=(r>>1)&3 invariant
    // under +16/+64 row offsets.
    const int swzR = (r >> 1) & 3;
    const u16* aRead = &As[0][0] + (waveM * 64 + r) * 32 + (q ^ swzR) * 8;
    const u16* bRead = &Bs[0][0] + (waveN * 64 + r) * 32 + (q ^ swzR) * 8;

#define STAGE(kOff, buf)                                                                     \
    do {                                                                                     \
        const int _b = (buf) * 8192; /* bytes per LDS buffer */                              \
        __builtin_amdgcn_global_load_lds((const AS1 u32*)(const void*)(aSrc0 + (kOff)),      \
                                         (AS3 u32*)(void*)(aDst0 + _b), 16, 0, 0);           \
        __builtin_amdgcn_global_load_lds((const AS1 u32*)(const void*)(aSrc1 + (kOff)),      \
                                         (AS3 u32*)(void*)(aDst1 + _b), 16, 0, 0);           \
        __builtin_amdgcn_global_load_lds((const AS1 u32*)(const void*)(bSrc0 + (kOff)),      \
                                         (AS3 u32*)(void*)(bDst0 + _b), 16, 0, 0);           \
        __builtin_amdgcn_global_load_lds((const AS1 u32*)(const void*)(bSrc1 + (kOff)),      \
                                         (AS3 u32*)(void*)(bDst1 + _b), 16, 0, 0);           \
    } while (0)

    STAGE(0, 0);
    __syncthreads();  // drain initial prefetch

    const int NKT = K_DIM / 32;
    for (int kt = 0; kt < NKT; ++kt) {
        const int cur = kt & 1;
        if (kt + 1 < NKT) STAGE((kt + 1) * 32, cur ^ 1);  // prefetch next tile, other buffer

        const u16* aR = aRead + cur * 4096;  // u16 elements per buffer
        const u16* bR = bRead + cur * 4096;
        short8 a[4], b[4];
#pragma unroll
        for (int mt = 0; mt < 4; ++mt) a[mt] = *(const short8*)(aR + mt * 16 * 32);
#pragma unroll
        for (int nt = 0; nt < 4; ++nt) b[nt] = *(const short8*)(bR + nt * 16 * 32);
#pragma unroll
        for (int mt = 0; mt < 4; ++mt)
#pragma unroll
            for (int nt = 0; nt < 4; ++nt)
                acc[mt][nt] = __builtin_amdgcn_mfma_f32_16x16x32_bf16(a[mt], b[nt], acc[mt][nt], 0, 0, 0);

        __syncthreads();  // one barrier per kt: readers done with buf cur, prefetch drained
    }
#undef STAGE

    // epilogue: C/D layout col(n)=lane&15, row(m)=q*4+reg; fuse per-channel scale
    const int mW = mBase + waveM * 64;
    const int nW = nBase + waveN * 64;
#pragma unroll
    for (int nt = 0; nt < 4; ++nt) {
        const int n = nW + nt * 16 + r;
        const float s = scaler[n];
#pragma unroll
        for (int mt = 0; mt < 4; ++mt) {
            const int m0 = mW + mt * 16 + q * 4;
#pragma unroll
            for (int j = 0; j < 4; ++j)
                out[(size_t)(m0 + j) * N_DIM + n] = acc[mt][nt][j] * s;
        }
    }
}

// ---------------- fallback (ws too small): fp32 vector GEMM, W as int32 ----------------
__global__ void __launch_bounds__(256)
gemm_fallback_kernel(const float* __restrict__ A, const int* __restrict__ W,
                     const float* __restrict__ scaler, float* __restrict__ out) {
    __shared__ float As[64][33];
    __shared__ float Ws[64][33];
    const int tx = threadIdx.x & 15, ty = threadIdx.x >> 4;
    const int mBase = blockIdx.y * 64, nBase = blockIdx.x * 64;
    float acc[4][4] = {};
    for (int kt = 0; kt < K_DIM; kt += 32) {
        for (int i = threadIdx.x; i < 64 * 32; i += 256) {
            int rr = i >> 5, cc = i & 31;
            As[rr][cc] = A[(size_t)(mBase + rr) * K_DIM + kt + cc];
            Ws[rr][cc] = (float)W[(size_t)(nBase + rr) * K_DIM + kt + cc];
        }
        __syncthreads();
        for (int kk = 0; kk < 32; ++kk) {
            float av[4], bv[4];
#pragma unroll
            for (int i = 0; i < 4; ++i) av[i] = As[ty * 4 + i][kk];
#pragma unroll
            for (int j = 0; j < 4; ++j) bv[j] = Ws[tx * 4 + j][kk];
#pragma unroll
            for (int i = 0; i < 4; ++i)
#pragma unroll
                for (int j = 0; j < 4; ++j) acc[i][j] += av[i] * bv[j];
        }
        __syncthreads();
    }
#pragma unroll
    for (int i = 0; i < 4; ++i)
#pragma unroll
        for (int j = 0; j < 4; ++j) {
            int m = mBase + ty * 4 + i, n = nBase + tx * 4 + j;
            out[(size_t)m * N_DIM + n] = acc[i][j] * scaler[n];
        }
}

extern "C" void kernel_launch(void* const* d_in, const int* in_sizes, int n_in,
                              void* d_out, int out_size, void* d_ws, size_t ws_size,
                              hipStream_t stream) {
    const float* A      = (const float*)d_in[0];
    const int*   W32    = (const int*)d_in[1];   // int8 values materialized as int32 (verified R1/R2)
    const float* scaler = (const float*)d_in[2];
    float* out          = (float*)d_out;

    const size_t needA = (size_t)M_DIM * K_DIM * sizeof(u16);  // 64 MiB
    const size_t needW = (size_t)N_DIM * K_DIM * sizeof(u16);  // 32 MiB

    if (ws_size >= needA + needW) {
        u16* Abf = (u16*)d_ws;
        u16* Wbf = (u16*)((char*)d_ws + needA);
        const int nA8 = M_DIM * K_DIM / 8;  // 4194304
        const int nW8 = N_DIM * K_DIM / 8;  // 2097152
        cvt_fused_kernel<<<3072, 256, 0, stream>>>((const float4*)A, (const int4*)W32,
                                                   (ushort8*)Abf, (ushort8*)Wbf, nA8, nW8);
        dim3 grid(N_DIM / 128, M_DIM / 128);  // x = N tiles so consecutive blocks share the A slice
        gemm_bf16_kernel<<<grid, 256, 0, stream>>>(Abf, Wbf, scaler, out);
    } else {
        dim3 grid(N_DIM / 64, M_DIM / 64);
        gemm_fallback_kernel<<<grid, 256, 0, stream>>>(A, W32, scaler, out);
    }
}